// Round 3
// baseline (467.612 us; speedup 1.0000x reference)
//
#include <hip/hip_runtime.h>

#define B_DIM   256
#define T_STEPS 2000
#define F_DIM   128
#define N_ROWS  (B_DIM * T_STEPS)         // 512000
#define N_GRP   (N_ROWS / 4)              // 128000 groups of 4 rows

// ---------------------------------------------------------------------------
// Kernel A: curT[t][b] = dot(x[b,t,:], W) + bias   (262 MB HBM stream)
// 16 lanes/row, reduction order bit-identical to the verified R1/R2 kernels.
// 2-stage software pipeline over the grid-stride loop.
// ---------------------------------------------------------------------------
__global__ __launch_bounds__(256) void dense_rows(
    const float* __restrict__ x, const float* __restrict__ W,
    const float* __restrict__ bias, float* __restrict__ curT) {
  const int tid    = threadIdx.x;
  const int lane   = tid & 63;
  const int sub    = lane & 15;   // float4 index within row (low half)
  const int grp    = lane >> 4;   // row within the wave's 4-row group
  const int waveId = (blockIdx.x * 256 + tid) >> 6;
  const int nWaves = gridDim.x * 4;

  const float4 wlo = ((const float4*)W)[sub];
  const float4 whi = ((const float4*)W)[sub + 16];
  const float  bs  = bias[0];

  float4 xl = make_float4(0.f, 0.f, 0.f, 0.f);
  float4 xh = make_float4(0.f, 0.f, 0.f, 0.f);
  if (waveId < N_GRP) {
    const float4* row = (const float4*)(x + (size_t)(waveId * 4 + grp) * F_DIM);
    xl = row[sub];
    xh = row[sub + 16];
  }

  for (int g = waveId; g < N_GRP; g += nWaves) {
    const int gn = g + nWaves;
    float4 nl = make_float4(0.f, 0.f, 0.f, 0.f);
    float4 nh = make_float4(0.f, 0.f, 0.f, 0.f);
    if (gn < N_GRP) {  // wave-uniform branch; prefetch next group's loads
      const float4* row = (const float4*)(x + (size_t)(gn * 4 + grp) * F_DIM);
      nl = row[sub];
      nh = row[sub + 16];
    }

    // --- bit-exact reduction (do not reorder) ---
    float pl = xl.x * wlo.x;
    pl = fmaf(xl.y, wlo.y, pl);
    pl = fmaf(xl.z, wlo.z, pl);
    pl = fmaf(xl.w, wlo.w, pl);
    float ph = xh.x * whi.x;
    ph = fmaf(xh.y, whi.y, ph);
    ph = fmaf(xh.z, whi.z, ph);
    ph = fmaf(xh.w, whi.w, ph);
    float s = pl + ph;                 // == p + shfl_xor(p,16)
    s += __shfl_xor(s, 8, 64);
    s += __shfl_xor(s, 4, 64);
    s += __shfl_xor(s, 2, 64);
    s += __shfl_xor(s, 1, 64);

    if (sub == 0) {
      const int rid0 = g * 4;
      const int b    = rid0 / T_STEPS;
      const int t0   = rid0 - b * T_STEPS;
      curT[(t0 + grp) * B_DIM + b] = s + bs;
    }
    xl = nl;
    xh = nh;
  }
}

// ---------------------------------------------------------------------------
// Kernel B: LIF scan, one lane per batch element, 4 blocks x 64 threads.
// cur staged global->LDS via global_load_lds (no VGPR pressure), dbuf tiles
// of 64 timesteps. Scan reads LDS with an 8-deep rolling register prefetch.
// Spikes staged in pitch-65 LDS; flushed at the START of the next tile so
// stores drain under the dependent chain.
// ---------------------------------------------------------------------------
__global__ __launch_bounds__(64) void lif_scan(
    const float* __restrict__ curT, float* __restrict__ out) {
  const float BETA = 0.8807970779778823f;  // sigmoid(2.0)

  __shared__ float cbuf[2][64 * 64];   // 32 KB: staged cur tiles [t][b]
  __shared__ float sp[64 * 65];        // 16.6 KB: spikes [batch][t], pitch 65

  const int lane = threadIdx.x;        // 0..63
  const int boff = blockIdx.x * 64;
  const int gb   = boff + lane;

  auto stage = [&](int k) {            // stage tile k into cbuf[k&1]
    const int t0  = k * 64;
    const int len = (T_STEPS - t0 < 64) ? (T_STEPS - t0) : 64;
    float* dst = cbuf[k & 1];
    for (int j = 0; j < len; ++j) {
      __builtin_amdgcn_global_load_lds(
          (const __attribute__((address_space(1))) void*)(
              curT + (size_t)(t0 + j) * B_DIM + boff + lane),
          (__attribute__((address_space(3))) void*)(dst + j * 64),
          4, 0, 0);
    }
  };

  float v = 0.0f;

  stage(0);
  __syncthreads();

  for (int k = 0; k < 32; ++k) {
    if (k + 1 < 32) stage(k + 1);      // loads in flight during this tile

    if (k > 0) {                       // flush previous tile's spikes
      const int tp = (k - 1) * 64;
#pragma unroll 8
      for (int r = 0; r < 64; ++r)
        out[(size_t)(boff + r) * T_STEPS + tp + lane] = sp[r * 65 + lane];
    }

    const float* cb  = cbuf[k & 1];
    const int    len = (T_STEPS - k * 64 < 64) ? (T_STEPS - k * 64) : 64;
    const int    ngrp = len >> 3;      // 8 or 2 groups of 8 steps

    float ra[8], rb[8];
#pragma unroll
    for (int j = 0; j < 8; ++j) ra[j] = cb[j * 64 + lane];

#pragma unroll
    for (int q = 0; q < 8; ++q) {
      if (q >= ngrp) break;            // tail tile: only 2 groups
      float* cur = (q & 1) ? rb : ra;
      float* nxt = (q & 1) ? ra : rb;
      if (q + 1 < ngrp) {
#pragma unroll
        for (int j = 0; j < 8; ++j)
          nxt[j] = cb[((q + 1) * 8 + j) * 64 + lane];
      }
#pragma unroll
      for (int j = 0; j < 8; ++j) {
        // vp = beta*v + c, two roundings (matches np elementwise semantics)
        const float vp   = __fadd_rn(__fmul_rn(BETA, v), cur[j]);
        const bool  fire = (vp >= 1.0f);          // == (vp - VTH >= 0)
        const float vr   = __fsub_rn(vp, 1.0f);   // == vp - s*VTH when s=1
        v = fire ? vr : vp;
        sp[lane * 65 + (q * 8 + j)] = fire ? 1.0f : 0.0f;
      }
    }
    __syncthreads();
  }

  // final flush: tile 31 covers t = 1984..1999 (16 steps)
  if (lane < 16) {
#pragma unroll 8
    for (int r = 0; r < 64; ++r)
      out[(size_t)(boff + r) * T_STEPS + 1984 + lane] = sp[r * 65 + lane];
  }

  out[(size_t)B_DIM * T_STEPS + gb] = v;   // final Vmem
}

extern "C" void kernel_launch(void* const* d_in, const int* in_sizes, int n_in,
                              void* d_out, int out_size, void* d_ws, size_t ws_size,
                              hipStream_t stream) {
  const float* x    = (const float*)d_in[0];
  const float* W    = (const float*)d_in[1];
  const float* bias = (const float*)d_in[2];
  float* out  = (float*)d_out;
  float* curT = (float*)d_ws;              // 512000 floats = 2.05 MB scratch

  dense_rows<<<dim3(2048), dim3(256), 0, stream>>>(x, W, bias, curT);
  lif_scan<<<dim3(B_DIM / 64), dim3(64), 0, stream>>>(curT, out);
}

// Round 4
// 363.698 us; speedup vs baseline: 1.2857x; 1.2857x over previous
//
#include <hip/hip_runtime.h>

#define B_DIM   256
#define T_STEPS 2000
#define F_DIM   128
#define TILE    256
#define NT      8     // 7 tiles of 256 + tail of 208

// Fused Dense(1) + LIF scan. One block per batch element (256 blocks, 1/CU),
// 1024 threads = 16 waves. All waves cooperatively load+reduce the NEXT
// 256-step tile of cur = x@W+b into a 2KB LDS double buffer while wave 0
// scans the CURRENT tile (redundantly across its 64 lanes; lane owns t&63
// -> coalesced 256B spike stores).
__global__ __launch_bounds__(1024) void lif_fused2(
    const float* __restrict__ x, const float* __restrict__ W,
    const float* __restrict__ bias, float* __restrict__ out, int B) {
  const float BETA = 0.8807970779778823f;  // sigmoid(2.0)

  __shared__ __align__(16) float buf[2][TILE];

  const int tid  = threadIdx.x;
  const int lane = tid & 63;
  const int wave = tid >> 6;    // 0..15
  const int sub  = lane & 15;   // float4 index within a row half
  const int grp  = lane >> 4;   // row within this wave's 4-row group
  const int b    = blockIdx.x;

  const float4 wlo = ((const float4*)W)[sub];
  const float4 whi = ((const float4*)W)[sub + 16];
  const float  bs  = bias[0];
  const float* xb  = x + (size_t)b * T_STEPS * F_DIM;
  float* outb = out + (size_t)b * T_STEPS;

  float4 xl[4], xh[4];
  float  v = 0.0f;

  auto tileLen = [&](int c) {
    const int t0 = c * TILE;
    return (T_STEPS - t0 < TILE) ? (T_STEPS - t0) : TILE;
  };

  auto loadRegs = [&](int c) {   // wave w owns tile rows [w*16, w*16+16)
    const int t0 = c * TILE, len = tileLen(c);
#pragma unroll
    for (int q = 0; q < 4; ++q) {
      const int tl = wave * 16 + q * 4;      // wave-uniform guard
      if (tl < len) {
        const float4* row = (const float4*)(xb + (size_t)(t0 + tl + grp) * F_DIM);
        xl[q] = row[sub];
        xh[q] = row[sub + 16];
      }
    }
  };

  auto reduceTo = [&](float* dst, int c) {
    const int len = tileLen(c);
#pragma unroll
    for (int q = 0; q < 4; ++q) {
      const int tl = wave * 16 + q * 4;
      if (tl < len) {
        // --- bit-exact reduction order (verified absmax 0.0) — do not reorder
        float pl = xl[q].x * wlo.x;
        pl = fmaf(xl[q].y, wlo.y, pl);
        pl = fmaf(xl[q].z, wlo.z, pl);
        pl = fmaf(xl[q].w, wlo.w, pl);
        float ph = xh[q].x * whi.x;
        ph = fmaf(xh[q].y, whi.y, ph);
        ph = fmaf(xh[q].z, whi.z, ph);
        ph = fmaf(xh[q].w, whi.w, ph);
        float s = pl + ph;                 // == p + shfl_xor(p,16)
        s += __shfl_xor(s, 8, 64);
        s += __shfl_xor(s, 4, 64);
        s += __shfl_xor(s, 2, 64);
        s += __shfl_xor(s, 1, 64);
        if (sub == 0) dst[tl + grp] = s + bs;
      }
    }
  };

  // Prologue: tile 0 -> buf[0]
  loadRegs(0);
  reduceTo(buf[0], 0);
  __syncthreads();

  for (int c = 0; c < NT; ++c) {
    if (c + 1 < NT) loadRegs(c + 1);   // loads in flight during scan/reduce

    if (wave == 0) {
      const float* cb  = buf[c & 1];
      const int    t0  = c * TILE;
      const int    len = tileLen(c);   // 256 or 208; both % 16 == 0
      const int    ng  = len >> 3;     // groups of 8 steps (32 or 26, even)
      float sreg = 0.0f;

      auto step = [&](float cvv, int tloc) {
        const float vp   = __fadd_rn(__fmul_rn(BETA, v), cvv);
        const bool  fire = (vp >= 1.0f);           // == (vp - VTH >= 0)
        v = fire ? __fsub_rn(vp, 1.0f) : vp;       // subtraction reset
        const float s = fire ? 1.0f : 0.0f;
        if ((tloc & 63) == lane) sreg = s;         // lane owns t&63
      };

      float4 A0 = *(const float4*)&cb[0];
      float4 A1 = *(const float4*)&cb[4];
      for (int gg = 0; gg < ng; gg += 2) {
        // prefetch odd group (gg+1 < ng always: ng even)
        float4 Bq0 = *(const float4*)&cb[(gg + 1) * 8];
        float4 Bq1 = *(const float4*)&cb[(gg + 1) * 8 + 4];
        step(A0.x, gg * 8 + 0); step(A0.y, gg * 8 + 1);
        step(A0.z, gg * 8 + 2); step(A0.w, gg * 8 + 3);
        step(A1.x, gg * 8 + 4); step(A1.y, gg * 8 + 5);
        step(A1.z, gg * 8 + 6); step(A1.w, gg * 8 + 7);
        if (gg + 2 < ng) {                         // prefetch next even group
          A0 = *(const float4*)&cb[(gg + 2) * 8];
          A1 = *(const float4*)&cb[(gg + 2) * 8 + 4];
        }
        const int tb = (gg + 1) * 8;
        step(Bq0.x, tb + 0); step(Bq0.y, tb + 1);
        step(Bq0.z, tb + 2); step(Bq0.w, tb + 3);
        step(Bq1.x, tb + 4); step(Bq1.y, tb + 5);
        step(Bq1.z, tb + 6); step(Bq1.w, tb + 7);
        if (((gg + 1) & 7) == 7) {                 // end of a 64-step round
          const int tend = tb + 7;                 // tend & 63 == 63
          outb[t0 + (tend - 63) + lane] = sreg;    // coalesced 256B store
        }
      }
      const int rem = len & 63;                    // 0 or 16 (tail tile)
      if (rem && lane < rem)
        outb[t0 + (len & ~63) + lane] = sreg;
    }

    if (c + 1 < NT) reduceTo(buf[(c + 1) & 1], c + 1);
    __syncthreads();
  }

  if (tid == 0) out[(size_t)B_DIM * T_STEPS + b] = v;  // final Vmem
}

extern "C" void kernel_launch(void* const* d_in, const int* in_sizes, int n_in,
                              void* d_out, int out_size, void* d_ws, size_t ws_size,
                              hipStream_t stream) {
  const float* x    = (const float*)d_in[0];
  const float* W    = (const float*)d_in[1];
  const float* bias = (const float*)d_in[2];
  float* out = (float*)d_out;
  const int B = in_sizes[0] / (T_STEPS * F_DIM);  // 256
  lif_fused2<<<dim3(B), dim3(1024), 0, stream>>>(x, W, bias, out, B);
}